// Round 1
// baseline (183.065 us; speedup 1.0000x reference)
//
#include <hip/hip_runtime.h>
#include <stdint.h>

#define N_NODES 8192
#define KPAD 272
#define OUTC 384

typedef __attribute__((ext_vector_type(8))) short bhalf8;
typedef __attribute__((ext_vector_type(16))) float f32x16;
typedef __attribute__((ext_vector_type(4))) float f32x4;

__device__ inline unsigned short f2bf_rne(float f) {
    unsigned u = __builtin_bit_cast(unsigned, f);
    u += 0x7FFFu + ((u >> 16) & 1u);
    return (unsigned short)(u >> 16);
}

__device__ inline bhalf8 mk8(unsigned a, unsigned b, unsigned c, unsigned d) {
    union { unsigned u[4]; bhalf8 v; } U;
    U.u[0] = a; U.u[1] = b; U.u[2] = c; U.u[3] = d;
    return U.v;
}

#define GLD_TO_LDS(gptr, lptr)                                                              \
    __builtin_amdgcn_global_load_lds((const __attribute__((address_space(1))) void*)(gptr), \
                                     (__attribute__((address_space(3))) void*)(lptr), 16, 0, 0)

// ---------------- prep: pack x (bf16, K-padded), WcatT, WrT, bcat ----------------
__global__ void k_prep(const float* __restrict__ landmarks, const float* __restrict__ features,
                       const float* __restrict__ Wi, const float* __restrict__ bi,
                       const float* __restrict__ Wj, const float* __restrict__ bj,
                       const float* __restrict__ Wk, const float* __restrict__ bk,
                       const float* __restrict__ Wr,
                       unsigned short* __restrict__ xb, unsigned short* __restrict__ WcatT,
                       unsigned short* __restrict__ WrT, float* __restrict__ bcat) {
    int idx = blockIdx.x * 256 + threadIdx.x;
    const int XB_N = N_NODES * KPAD;   // 2,228,224
    const int WC_N = OUTC * KPAD;      // 104,448
    const int WR_N = 256 * 128;        // 32,768
    if (idx < XB_N) {
        int i = idx / KPAD, kk = idx - i * KPAD;
        float v = 0.f;
        if (kk < 256) v = features[i * 256 + kk];
        else if (kk < 259) v = landmarks[i * 3 + (kk - 256)];
        xb[idx] = f2bf_rne(v);
        return;
    }
    idx -= XB_N;
    if (idx < WC_N) {
        int n = idx / KPAD, kk = idx - n * KPAD;
        int sel = n >> 7, d = n & 127;
        const float* W = (sel == 0) ? Wi : ((sel == 1) ? Wj : Wk);
        float v = 0.f;
        if (kk < 256) v = W[(kk + 3) * 128 + d];
        else if (kk < 259) v = W[(kk - 256) * 128 + d];
        WcatT[idx] = f2bf_rne(v);
        return;
    }
    idx -= WC_N;
    if (idx < WR_N) {
        int c = idx >> 7, d = idx & 127;
        WrT[idx] = f2bf_rne(Wr[d * 256 + c]);
        return;
    }
    idx -= WR_N;
    if (idx < OUTC) {
        float v = (idx < 128) ? bi[idx] : ((idx < 256) ? bj[idx - 128] : bk[idx - 256]);
        bcat[idx] = v;
    }
}

// ---------------- k1: projections f = xb @ WcatT^T(+bias) -> fi, fj, fkT ----------------
__global__ __launch_bounds__(256) void k_proj(const unsigned short* __restrict__ xb,
                                              const unsigned short* __restrict__ WcatT,
                                              const float* __restrict__ bcat,
                                              unsigned short* __restrict__ fi,
                                              unsigned short* __restrict__ fj,
                                              unsigned short* __restrict__ fkT) {
    const int tid = threadIdx.x;
    const int w = tid >> 6, l = tid & 63, h = l >> 5, ln = l & 31;
    const int i0 = blockIdx.x * 32;
    f32x16 acc[3] = {};
#pragma unroll
    for (int s = 0; s < 17; ++s) {
        bhalf8 a = *(const bhalf8*)(xb + (size_t)(i0 + ln) * KPAD + s * 16 + h * 8);
#pragma unroll
        for (int t = 0; t < 3; ++t) {
            int n = 96 * w + 32 * t + ln;
            bhalf8 b = *(const bhalf8*)(WcatT + (size_t)n * KPAD + s * 16 + h * 8);
            acc[t] = __builtin_amdgcn_mfma_f32_32x32x16_bf16(a, b, acc[t], 0, 0, 0);
        }
    }
#pragma unroll
    for (int t = 0; t < 3; ++t) {
        int n = 96 * w + 32 * t + ln;
        int sel = n >> 7, d = n & 127;
        float bias = bcat[n];
#pragma unroll
        for (int q = 0; q < 4; ++q) {
            int ib = i0 + 8 * q + 4 * h;
            if (sel < 2) {
                unsigned short* dst = sel ? fj : fi;
#pragma unroll
                for (int r = 0; r < 4; ++r)
                    dst[(size_t)(ib + r) * 128 + d] = f2bf_rne(acc[t][4 * q + r] + bias);
            } else {
                ushort4 pk;
                pk.x = f2bf_rne(acc[t][4 * q + 0] + bias);
                pk.y = f2bf_rne(acc[t][4 * q + 1] + bias);
                pk.z = f2bf_rne(acc[t][4 * q + 2] + bias);
                pk.w = f2bf_rne(acc[t][4 * q + 3] + bias);
                *(ushort4*)(fkT + (size_t)d * N_NODES + ib) = pk;
            }
        }
    }
}

// ---------------- k2: fused sigmoid-attention (num/den partials per j-quarter) ----------------
__global__ __launch_bounds__(256, 2) void k_attn(const unsigned short* __restrict__ fi,
                                                 const unsigned short* __restrict__ fj,
                                                 const unsigned short* __restrict__ fkT,
                                                 float* __restrict__ num_part,
                                                 float* __restrict__ den_part) {
    __shared__ __align__(16) char smem[65536];
    unsigned short* fj_s = (unsigned short*)smem;             // [128][128] xor-swizzled, 32 KB
    unsigned short* fk_s = (unsigned short*)(smem + 32768);   // [128 d][128 j] swizzled, 32 KB
    float* bufA = (float*)smem;                               // [64][68] reduce buffer
    float* bufB = (float*)(smem + 17408);
    float* denb = (float*)(smem + 34816);                     // [4][64]

    const int tid = threadIdx.x;
    const int w = tid >> 6, l = tid & 63, h = l >> 5, ln = l & 31;
    const int rt = blockIdx.x & 127, jq = blockIdx.x >> 7;
    const int i0 = rt * 64;
    const int jbase = jq * 2048;

    // hoist fi B-fragments (64 VGPRs), reused across all j
    bhalf8 bfi[2][8];
#pragma unroll
    for (int nt = 0; nt < 2; ++nt)
#pragma unroll
        for (int s = 0; s < 8; ++s)
            bfi[nt][s] = *(const bhalf8*)(fi + (size_t)(i0 + nt * 32 + ln) * 128 + s * 16 + h * 8);

    f32x16 acc[8] = {};       // numT tiles: [d-tile 0..3][i-tile 0..1]
    float dacc0 = 0.f, dacc1 = 0.f;

    const int rsub = l >> 4;  // staging: row-within-4
    const int cph = l & 15;   // staging: physical chunk

    for (int mt = 0; mt < 16; ++mt) {
        const int j0 = jbase + mt * 128;
#pragma unroll
        for (int q = 0; q < 8; ++q) {
            int r = w * 32 + q * 4 + rsub;
            int c = cph ^ (r & 15);
            GLD_TO_LDS(fj + (size_t)(j0 + r) * 128 + c * 8, (char*)fj_s + (w * 32 + q * 4) * 256);
            GLD_TO_LDS(fkT + (size_t)r * N_NODES + j0 + c * 8, (char*)fk_s + (w * 32 + q * 4) * 256);
        }
        __syncthreads();

        // S^T = fj @ fi^T  (wave's 32-j chunk x 64 i)
        f32x16 st0 = {}, st1 = {};
        const int jrow = w * 32 + ln;
#pragma unroll
        for (int s = 0; s < 8; ++s) {
            int c = (s * 2 + h) ^ (jrow & 15);
            bhalf8 af = *(const bhalf8*)((char*)fj_s + jrow * 256 + c * 16);
            st0 = __builtin_amdgcn_mfma_f32_32x32x16_bf16(af, bfi[0][s], st0, 0, 0, 0);
            st1 = __builtin_amdgcn_mfma_f32_32x32x16_bf16(af, bfi[1][s], st1, 0, 0, 0);
        }

        // sigmoid + denom accumulate (values stay as P^T in C-layout)
        float sv0[16], sv1[16];
#pragma unroll
        for (int r = 0; r < 16; ++r) {
            float x0 = __builtin_amdgcn_rcpf(1.f + __builtin_amdgcn_exp2f(st0[r] * -1.44269504f));
            float x1 = __builtin_amdgcn_rcpf(1.f + __builtin_amdgcn_exp2f(st1[r] * -1.44269504f));
            dacc0 += x0; dacc1 += x1;
            sv0[r] = x0; sv1[r] = x1;
        }
        // pack consecutive-j pairs to bf16 (truncation; bias cancels in normalization)
        unsigned p0[8], p1[8], x0v[8], x1v[8];
#pragma unroll
        for (int q = 0; q < 8; ++q) {
            p0[q] = __builtin_amdgcn_perm(__builtin_bit_cast(unsigned, sv0[2 * q + 1]),
                                          __builtin_bit_cast(unsigned, sv0[2 * q]), 0x07060302u);
            p1[q] = __builtin_amdgcn_perm(__builtin_bit_cast(unsigned, sv1[2 * q + 1]),
                                          __builtin_bit_cast(unsigned, sv1[2 * q]), 0x07060302u);
        }
#pragma unroll
        for (int q = 0; q < 8; ++q) {
            x0v[q] = (unsigned)__shfl_xor((int)p0[q], 32, 64);
            x1v[q] = (unsigned)__shfl_xor((int)p1[q], 32, 64);
        }
        // assemble P^T B-operand fragments (k = j_local)
        bhalf8 fb[2][2];
        if (h == 0) {
            fb[0][0] = mk8(p0[0], p0[1], x0v[0], x0v[1]);
            fb[0][1] = mk8(p0[4], p0[5], x0v[4], x0v[5]);
            fb[1][0] = mk8(p1[0], p1[1], x1v[0], x1v[1]);
            fb[1][1] = mk8(p1[4], p1[5], x1v[4], x1v[5]);
        } else {
            fb[0][0] = mk8(x0v[2], x0v[3], p0[2], p0[3]);
            fb[0][1] = mk8(x0v[6], x0v[7], p0[6], p0[7]);
            fb[1][0] = mk8(x1v[2], x1v[3], p1[2], p1[3]);
            fb[1][1] = mk8(x1v[6], x1v[7], p1[6], p1[7]);
        }
        // PV: numT[d][i] += fkT[d][j] * P^T[j][i]
#pragma unroll
        for (int m4 = 0; m4 < 4; ++m4) {
#pragma unroll
            for (int s2 = 0; s2 < 2; ++s2) {
                int row = m4 * 32 + ln;
                int c = (w * 4 + s2 * 2 + h) ^ (row & 15);
                bhalf8 af = *(const bhalf8*)((char*)fk_s + row * 256 + c * 16);
                acc[m4 * 2 + 0] = __builtin_amdgcn_mfma_f32_32x32x16_bf16(af, fb[0][s2], acc[m4 * 2 + 0], 0, 0, 0);
                acc[m4 * 2 + 1] = __builtin_amdgcn_mfma_f32_32x32x16_bf16(af, fb[1][s2], acc[m4 * 2 + 1], 0, 0, 0);
            }
        }
        __syncthreads();
    }

    // denom: fold lane l <-> l^32, then stash per-wave
    {
        float o0 = __shfl_xor(dacc0, 32, 64);
        float o1 = __shfl_xor(dacc1, 32, 64);
        dacc0 += o0; dacc1 += o1;
    }
    if (h == 0) {
        denb[w * 64 + ln] = dacc0;
        denb[w * 64 + 32 + ln] = dacc1;
    }

    // cross-wave num reduce in two d-halves (reuses staging LDS)
#pragma unroll
    for (int half = 0; half < 2; ++half) {
        __syncthreads();
        if (w < 2) {
            float* buf = w ? bufB : bufA;
#pragma unroll
            for (int m2 = 0; m2 < 2; ++m2) {
                int m4 = half * 2 + m2;
#pragma unroll
                for (int nt = 0; nt < 2; ++nt) {
                    int iloc = nt * 32 + ln;
#pragma unroll
                    for (int q = 0; q < 4; ++q) {
                        int d = m2 * 32 + 8 * q + 4 * h;
                        f32x4 v = {acc[m4 * 2 + nt][4 * q + 0], acc[m4 * 2 + nt][4 * q + 1],
                                   acc[m4 * 2 + nt][4 * q + 2], acc[m4 * 2 + nt][4 * q + 3]};
                        *(f32x4*)(buf + iloc * 68 + d) = v;
                    }
                }
            }
        }
        __syncthreads();
        if (w >= 2) {
            float* buf = (w == 3) ? bufB : bufA;
#pragma unroll
            for (int m2 = 0; m2 < 2; ++m2) {
                int m4 = half * 2 + m2;
#pragma unroll
                for (int nt = 0; nt < 2; ++nt) {
                    int iloc = nt * 32 + ln;
#pragma unroll
                    for (int q = 0; q < 4; ++q) {
                        int d = m2 * 32 + 8 * q + 4 * h;
                        f32x4 old = *(f32x4*)(buf + iloc * 68 + d);
                        f32x4 v = {acc[m4 * 2 + nt][4 * q + 0], acc[m4 * 2 + nt][4 * q + 1],
                                   acc[m4 * 2 + nt][4 * q + 2], acc[m4 * 2 + nt][4 * q + 3]};
                        *(f32x4*)(buf + iloc * 68 + d) = old + v;
                    }
                }
            }
        }
        __syncthreads();
#pragma unroll
        for (int e = 0; e < 4; ++e) {
            int v = e * 256 + tid;           // 1024 float4s = 64 i x 16
            int iloc = v >> 4;
            int d4 = (v & 15) * 4;
            f32x4 s = *(f32x4*)(bufA + iloc * 68 + d4) + *(f32x4*)(bufB + iloc * 68 + d4);
            *(f32x4*)(num_part + (size_t)(jq * N_NODES + i0 + iloc) * 128 + half * 64 + d4) = s;
        }
    }
    __syncthreads();
    if (tid < 64) {
        den_part[(size_t)jq * N_NODES + i0 + tid] =
            denb[tid] + denb[64 + tid] + denb[128 + tid] + denb[192 + tid];
    }
}

// ---------------- k2b: t = (sum num)/(sum den) -> bf16 ----------------
__global__ void k_comb(const float* __restrict__ num_part, const float* __restrict__ den_part,
                       unsigned short* __restrict__ t) {
    int f = blockIdx.x * 256 + threadIdx.x;   // 262144 float4 groups
    int i = f >> 5, d4 = (f & 31) * 4;
    f32x4 s = {};
    float ds = 0.f;
#pragma unroll
    for (int q = 0; q < 4; ++q) {
        s += *(const f32x4*)(num_part + (size_t)(q * N_NODES + i) * 128 + d4);
        ds += den_part[(size_t)q * N_NODES + i];
    }
    float inv = 1.0f / ds;
    ushort4 pk;
    pk.x = f2bf_rne(s.x * inv);
    pk.y = f2bf_rne(s.y * inv);
    pk.z = f2bf_rne(s.z * inv);
    pk.w = f2bf_rne(s.w * inv);
    *(ushort4*)(t + (size_t)i * 128 + d4) = pk;
}

// ---------------- k3: out = t @ Wr + br + features ----------------
__global__ __launch_bounds__(256) void k_out(const unsigned short* __restrict__ t,
                                             const unsigned short* __restrict__ WrT,
                                             const float* __restrict__ br,
                                             const float* __restrict__ features,
                                             float* __restrict__ out) {
    __shared__ __align__(16) char smem[65536];
    const int tid = threadIdx.x, w = tid >> 6, l = tid & 63, h = l >> 5, ln = l & 31;
    const int i0 = blockIdx.x * 32;
    {
        int rsub = l >> 4, cph = l & 15;
#pragma unroll
        for (int q = 0; q < 16; ++q) {
            int r = w * 64 + q * 4 + rsub;
            int c = cph ^ (r & 15);
            GLD_TO_LDS(WrT + (size_t)r * 128 + c * 8, (char*)smem + (w * 64 + q * 4) * 256);
        }
    }
    __syncthreads();
    f32x16 acc[2] = {};
#pragma unroll
    for (int s = 0; s < 8; ++s) {
        bhalf8 af = *(const bhalf8*)(t + (size_t)(i0 + ln) * 128 + s * 16 + h * 8);
#pragma unroll
        for (int nt = 0; nt < 2; ++nt) {
            int row = w * 64 + nt * 32 + ln;
            int c = (s * 2 + h) ^ (row & 15);
            bhalf8 bf = *(const bhalf8*)((char*)smem + row * 256 + c * 16);
            acc[nt] = __builtin_amdgcn_mfma_f32_32x32x16_bf16(af, bf, acc[nt], 0, 0, 0);
        }
    }
#pragma unroll
    for (int nt = 0; nt < 2; ++nt) {
        int cc = w * 64 + nt * 32 + ln;
        float bias = br[cc];
#pragma unroll
        for (int q = 0; q < 4; ++q) {
#pragma unroll
            for (int r = 0; r < 4; ++r) {
                int i = i0 + 8 * q + 4 * h + r;
                out[(size_t)i * 256 + cc] = acc[nt][4 * q + r] + bias + features[(size_t)i * 256 + cc];
            }
        }
    }
}

extern "C" void kernel_launch(void* const* d_in, const int* in_sizes, int n_in,
                              void* d_out, int out_size, void* d_ws, size_t ws_size,
                              hipStream_t stream) {
    const float* landmarks = (const float*)d_in[0];
    const float* features  = (const float*)d_in[1];
    const float* Wi = (const float*)d_in[2];
    const float* bi = (const float*)d_in[3];
    const float* Wj = (const float*)d_in[4];
    const float* bj = (const float*)d_in[5];
    const float* Wk = (const float*)d_in[6];
    const float* bk = (const float*)d_in[7];
    const float* Wr = (const float*)d_in[8];
    const float* br = (const float*)d_in[9];

    char* ws = (char*)d_ws;
    unsigned short* xb      = (unsigned short*)(ws + 0);         // 8192x272 bf16
    unsigned short* WcatT   = (unsigned short*)(ws + 4456448);   // 384x272 bf16
    unsigned short* WrT     = (unsigned short*)(ws + 4665344);   // 256x128 bf16
    float*          bcat    = (float*)(ws + 4730880);            // 384 f32
    unsigned short* fi      = (unsigned short*)(ws + 4732416);   // 8192x128 bf16
    unsigned short* fjp     = (unsigned short*)(ws + 6829568);   // 8192x128 bf16
    unsigned short* fkT     = (unsigned short*)(ws + 8926720);   // 128x8192 bf16
    float*          num_part= (float*)(ws + 11023872);           // 4x8192x128 f32
    float*          den_part= (float*)(ws + 27801088);           // 4x8192 f32
    unsigned short* t       = (unsigned short*)(ws + 27932160);  // 8192x128 bf16

    float* out = (float*)d_out;

    hipLaunchKernelGGL(k_prep, dim3(9242), dim3(256), 0, stream,
                       landmarks, features, Wi, bi, Wj, bj, Wk, bk, Wr, xb, WcatT, WrT, bcat);
    hipLaunchKernelGGL(k_proj, dim3(256), dim3(256), 0, stream, xb, WcatT, bcat, fi, fjp, fkT);
    hipLaunchKernelGGL(k_attn, dim3(512), dim3(256), 0, stream, fi, fjp, fkT, num_part, den_part);
    hipLaunchKernelGGL(k_comb, dim3(1024), dim3(256), 0, stream, num_part, den_part, t);
    hipLaunchKernelGGL(k_out, dim3(256), dim3(256), 0, stream, t, WrT, br, features, out);
}